// Round 18
// baseline (141.012 us; speedup 1.0000x reference)
//
#include <hip/hip_runtime.h>
#include <math.h>

#define CC 10   // classes
#define KK 50   // neighbors

typedef float f2_t __attribute__((ext_vector_type(2)));

// ---- kA: 64 rows/block, 8 waves each own a NEIGHBOR SLICE of all 64 rows ---
// 8192 waves = 32 waves/CU (hw max) -> max memory concurrency (R17 confirmed
// concurrency as the binder: 4->16 waves/CU gave 0.88->1.6 TB/s). nbr stream
// loaded NONTEMPORALLY: kA gets ~no L3 hits anyway, and this preserves L2/L3
// for the tail kernels' working set (R17's +17us tail regression).
__global__ __launch_bounds__(512)
void kA(const float* __restrict__ aw, const float* __restrict__ an,
        const float* __restrict__ nbr, const float* __restrict__ att,
        const float* __restrict__ proj,
        float* __restrict__ wap, float* __restrict__ beta,
        int* __restrict__ flag0, int* __restrict__ hist, int B)
{
  __shared__ float part[7][64][13];         // waves 1..7 partials (stride-13: conflict-free)

  int tid  = threadIdx.x;
  int wave = tid >> 6;
  int lane = tid & 63;
  int row  = blockIdx.x * 64 + lane;
  bool valid = (row < B);
  int lrow = valid ? row : 0;               // clamp for safe loads

  // uniform coef (scalar loads): coef[c] = att[c] * proj[c][c]^2
  float coef[CC];
#pragma unroll
  for (int c = 0; c < CC; ++c) { float d = proj[c * CC + c]; coef[c] = att[c] * d * d; }

  // anchors row -> ci (redundant per wave; tiny, L1/L2 shared)
  const float2* anp = reinterpret_cast<const float2*>(an + (size_t)lrow * CC);
  float av[CC];
#pragma unroll
  for (int c2 = 0; c2 < CC / 2; ++c2) { float2 t = anp[c2]; av[2*c2] = t.x; av[2*c2+1] = t.y; }
  float ci[CC];
#pragma unroll
  for (int c = 0; c < CC; ++c) ci[c] = coef[c] * av[c];

  float den = 0.f;
  float qh[CC];
#pragma unroll
  for (int c = 0; c < CC; ++c) qh[c] = 0.f;

  // this wave's neighbor slice: starts {0,7,14,20,26,32,38,44}, counts {7,7,6,...}
  int ks = (wave < 2) ? wave * 7 : 14 + (wave - 2) * 6;
  int kc = (wave < 2) ? 7 : 6;
  const f2_t* rowp = reinterpret_cast<const f2_t*>(nbr + (size_t)lrow * (KK * CC))
                     + ks * (CC / 2);

#pragma unroll
  for (int t = 0; t < 7; ++t) {
    if (t >= kc) break;                     // wave-uniform
    float nb[CC];
#pragma unroll
    for (int c2 = 0; c2 < CC / 2; ++c2) {
      f2_t v = __builtin_nontemporal_load(&rowp[t * (CC / 2) + c2]);
      nb[2*c2] = v.x; nb[2*c2+1] = v.y;
    }
    float s = 0.f;
#pragma unroll
    for (int c = 0; c < CC; ++c) s = fmaf(ci[c], nb[c], s);
    s = (s > 0.f) ? s : 0.01f * s;          // leaky_relu (inputs O(1), exp-safe)
    float en[CC]; float sn = 0.f;
#pragma unroll
    for (int c = 0; c < CC; ++c) { en[c] = __expf(nb[c]); sn += en[c]; }
    float e = __expf(s);
    den += e;
    float esc = e * __builtin_amdgcn_rcpf(sn);
#pragma unroll
    for (int c = 0; c < CC; ++c) qh[c] = fmaf(esc, en[c], qh[c]);
  }

  if (wave > 0) {
    part[wave - 1][lane][0] = den;
#pragma unroll
    for (int c = 0; c < CC; ++c) part[wave - 1][lane][1 + c] = qh[c];
  }
  __syncthreads();
  if (wave != 0) return;

  // wave 0: merge partials (fixed order: reassociation only)
#pragma unroll
  for (int w = 0; w < 7; ++w) {
    den += part[w][lane][0];
#pragma unroll
    for (int c = 0; c < CC; ++c) qh[c] += part[w][lane][1 + c];
  }
  if (!valid) return;
  float invd = __builtin_amdgcn_rcpf(den);

  // beta = || softmax(an row) - qh/den ||^2
  float ap[CC]; float s2 = 0.f;
#pragma unroll
  for (int c = 0; c < CC; ++c) { ap[c] = __expf(av[c]); s2 += ap[c]; }
  float inv2 = __builtin_amdgcn_rcpf(s2);
  float dd = 0.f;
#pragma unroll
  for (int c = 0; c < CC; ++c) { float d1 = ap[c] * inv2 - qh[c] * invd; dd = fmaf(d1, d1, dd); }
  beta[row] = dd;

  // wap = softmax(aw row); flag0; hist
  const float2* awp = reinterpret_cast<const float2*>(aw + (size_t)row * CC);
  float wv[CC];
#pragma unroll
  for (int c2 = 0; c2 < CC / 2; ++c2) { float2 t = awp[c2]; wv[2*c2] = t.x; wv[2*c2+1] = t.y; }
  float ew[CC]; float sw = 0.f, mxw = 0.f;
#pragma unroll
  for (int c = 0; c < CC; ++c) { ew[c] = __expf(wv[c]); sw += ew[c]; mxw = fmaxf(mxw, ew[c]); }
  float rsw = __builtin_amdgcn_rcpf(sw);
  float2* wq = reinterpret_cast<float2*>(wap + (size_t)row * CC);
#pragma unroll
  for (int c2 = 0; c2 < CC / 2; ++c2) {
    float2 t; t.x = ew[2*c2] * rsw; t.y = ew[2*c2+1] * rsw; wq[c2] = t;
  }
  int f = (mxw * rsw > 0.15f) ? 1 : 0;
  flag0[row] = f;
  if (f) atomicAdd(&hist[__float_as_uint(dd) >> 16], 1);  // beta>=0: order-preserving
}

// ---------------- K3: exact radix select of k-th smallest beta --------------
// scal: [2]=sel_hi [3]=k2 [4]=k ; (float at [8]) = tau
__global__ __launch_bounds__(1024)
void k3b_sel(const int* __restrict__ hist, int* __restrict__ scal)
{
  __shared__ int tmp[1024];
  int t = threadIdx.x;
  int base = t * 64;
  const int4* h4 = reinterpret_cast<const int4*>(hist + base);
  int sum = 0;
#pragma unroll
  for (int jj = 0; jj < 16; ++jj) { int4 v = h4[jj]; sum += v.x + v.y + v.z + v.w; }
  tmp[t] = sum;
  __syncthreads();
  for (int off = 1; off < 1024; off <<= 1) {
    int v = (t >= off) ? tmp[t - off] : 0;
    __syncthreads();
    tmp[t] += v;
    __syncthreads();
  }
  int cumb = tmp[t] - sum;
  int b = tmp[1023];                 // total flagged count == b_count
  int k = (int)(0.5 * (double)b);    // int(ETA*b)
  if (k < 1) k = 1;
  if (t == 0) scal[4] = k;
  if (b > 0 && k > cumb && k <= cumb + sum) {
    int c = cumb;
    for (int jj = 0; jj < 64; ++jj) {
      int h = hist[base + jj];
      if (k <= c + h) { scal[2] = base + jj; scal[3] = k - c; break; }
      c += h;
    }
  }
  if (b == 0 && t == 0) { scal[2] = 0; scal[3] = 1; }
}

__global__ __launch_bounds__(256)
void k3c_hist2(const float* __restrict__ beta, const int* __restrict__ flag0,
               const int* __restrict__ scal, int* __restrict__ hist2, int B)
{
  int i = blockIdx.x * 256 + threadIdx.x;
  if (i >= B) return;
  if (flag0[i]) {
    unsigned key = __float_as_uint(beta[i]);
    if ((int)(key >> 16) == scal[2]) atomicAdd(&hist2[key & 0xFFFF], 1);
  }
}

__global__ __launch_bounds__(1024)
void k3d_tau(const int* __restrict__ hist2, int* __restrict__ scal,
             float* __restrict__ tau)
{
  __shared__ int tmp[1024];
  int t = threadIdx.x;
  int base = t * 64;
  const int4* h4 = reinterpret_cast<const int4*>(hist2 + base);
  int sum = 0;
#pragma unroll
  for (int jj = 0; jj < 16; ++jj) { int4 v = h4[jj]; sum += v.x + v.y + v.z + v.w; }
  tmp[t] = sum;
  __syncthreads();
  for (int off = 1; off < 1024; off <<= 1) {
    int v = (t >= off) ? tmp[t - off] : 0;
    __syncthreads();
    tmp[t] += v;
    __syncthreads();
  }
  int cumb = tmp[t] - sum;
  int k2 = scal[3];
  if (k2 > cumb && k2 <= cumb + sum) {
    int c = cumb;
    for (int jj = 0; jj < 64; ++jj) {
      int h = hist2[base + jj];
      if (k2 <= c + h) {
        unsigned key = (((unsigned)scal[2]) << 16) | (unsigned)(base + jj);
        float bk = __uint_as_float(key);
        *tau = bk / expf(-1.0f);
        break;
      }
      c += h;
    }
  }
}

// ---------------- K4: q, target, mask1, per-block counts --------------------
__global__ __launch_bounds__(256)
void k4_q(const float* __restrict__ wap, const float* __restrict__ beta,
          const int* __restrict__ flag0, const float* __restrict__ tau_p,
          float* __restrict__ qbuf, int* __restrict__ target, int* __restrict__ flag1,
          int* __restrict__ counts, int* __restrict__ blockcnt, int B)
{
  __shared__ int lcnt[CC];
  if (threadIdx.x < CC) lcnt[threadIdx.x] = 0;
  __syncthreads();

  int i = blockIdx.x * 256 + threadIdx.x;
  int f = 0;
  if (i < B) {
    float tau = *tau_p;
    float w[CC];
    const float2* p = reinterpret_cast<const float2*>(wap + (size_t)i * CC);
#pragma unroll
    for (int c = 0; c < CC / 2; ++c) { float2 t = p[c]; w[2*c] = t.x; w[2*c+1] = t.y; }
    float alpha = -__logf(beta[i] / tau);
    float q[CC];
    if (alpha > 1.0f) {
      float s = 0.f;
#pragma unroll
      for (int c = 0; c < CC; ++c) { q[c] = __expf(alpha * __logf(w[c])); s += q[c]; }
#pragma unroll
      for (int c = 0; c < CC; ++c) q[c] = q[c] / s;
    } else {
#pragma unroll
      for (int c = 0; c < CC; ++c) q[c] = w[c];
    }
    float mp = q[0]; int tg = 0;
#pragma unroll
    for (int c = 1; c < CC; ++c) if (q[c] > mp) { mp = q[c]; tg = c; }
    f = (flag0[i] && (mp > 0.1f)) ? 1 : 0;
    float2* qo = reinterpret_cast<float2*>(qbuf + (size_t)i * CC);
#pragma unroll
    for (int c = 0; c < CC / 2; ++c) { float2 t; t.x = q[2*c]; t.y = q[2*c+1]; qo[c] = t; }
    target[i] = tg;
    flag1[i] = f;
    if (f) atomicAdd(&lcnt[tg], 1);   // LDS atomic, contained in block
  }
  __shared__ int red[256];
  red[threadIdx.x] = f;
  __syncthreads();
  for (int off = 128; off; off >>= 1) {
    if (threadIdx.x < off) red[threadIdx.x] += red[threadIdx.x + off];
    __syncthreads();
  }
  if (threadIdx.x == 0) blockcnt[blockIdx.x] = red[0];
  if (threadIdx.x < CC) {
    int v = lcnt[threadIdx.x];
    if (v) atomicAdd(&counts[threadIdx.x], v);   // <=10 global atomics per block
  }
}

// ---------------- K6: self-scan block offsets, weights, outputs, loss parts -
__global__ __launch_bounds__(256)
void k6_out(const int* __restrict__ flag1, const int* __restrict__ target,
            const int* __restrict__ labels, const int* __restrict__ blockcnt,
            const float* __restrict__ a_strong, const float* __restrict__ qbuf,
            const int* __restrict__ counts, float* __restrict__ out,
            float* __restrict__ lossp, int n_host, int nb, int B)
{
  __shared__ int tmp[256];
  __shared__ float wavg_s[CC];
  int t = threadIdx.x;

  int bv = (t < nb) ? blockcnt[t] : 0;
  tmp[t] = bv;
  __syncthreads();
  for (int off = 1; off < 256; off <<= 1) {
    int u = (t >= off) ? tmp[t - off] : 0;
    __syncthreads();
    tmp[t] += u;
    __syncthreads();
  }
  int n    = tmp[255];
  int boff = (blockIdx.x > 0) ? tmp[blockIdx.x - 1] : 0;
  if (t == 0) {
    float wt[CC]; float sumw = 0.f;
    for (int c = 0; c < CC; ++c) {
      int cnt = counts[c];
      float w_ = (cnt > 0) ? 1.0f / logf(1.02f + (float)cnt / (float)n) : 1.0f;
      wt[c] = w_; sumw += w_;
    }
    float meanw = sumw / (float)CC;
    for (int c = 0; c < CC; ++c) wavg_s[c] = wt[c] / sumw * meanw;
  }
  __syncthreads();

  int i = blockIdx.x * 256 + t;
  int f = (i < B) ? flag1[i] : 0;
  tmp[t] = f;
  __syncthreads();
  for (int off = 1; off < 256; off <<= 1) {
    int u = (t >= off) ? tmp[t - off] : 0;
    __syncthreads();
    tmp[t] += u;
    __syncthreads();
  }
  int pos = boff + tmp[t] - f;
  float part = 0.f;
  if (f) {
    out[1 + pos] = (float)target[i];
    out[1 + n_host + pos] = (float)labels[i];
    float x[CC];
    const float2* p = reinterpret_cast<const float2*>(a_strong + (size_t)i * CC);
#pragma unroll
    for (int c = 0; c < CC / 2; ++c) { float2 u2 = p[c]; x[2*c] = u2.x; x[2*c+1] = u2.y; }
    float m = x[0];
#pragma unroll
    for (int c = 1; c < CC; ++c) m = fmaxf(m, x[c]);
    float s = 0.f;
#pragma unroll
    for (int c = 0; c < CC; ++c) s += __expf(x[c] - m);
    float lse = m + __logf(s);
    const float2* qp = reinterpret_cast<const float2*>(qbuf + (size_t)i * CC);
    float q[CC];
#pragma unroll
    for (int c = 0; c < CC / 2; ++c) { float2 u2 = qp[c]; q[2*c] = u2.x; q[2*c+1] = u2.y; }
#pragma unroll
    for (int c = 0; c < CC; ++c) part += wavg_s[c] * q[c] * (x[c] - lse);
  }
  __shared__ float red[256];
  red[t] = part;
  __syncthreads();
  for (int off = 128; off; off >>= 1) {
    if (t < off) red[t] += red[t + off];
    __syncthreads();
  }
  if (t == 0) lossp[blockIdx.x] = red[0];
}

// ---------------- K7: finalize ----------------------------------------------
__global__ __launch_bounds__(256)
void k7_fin(const float* __restrict__ lossp, int nb, const int* __restrict__ blockcnt,
            float* __restrict__ out, int n_host)
{
  __shared__ float red[256];
  __shared__ int   redi[256];
  int t = threadIdx.x;
  float s = 0.f; int ns = 0;
  for (int jj = t; jj < nb; jj += 256) { s += lossp[jj]; ns += blockcnt[jj]; }
  red[t] = s; redi[t] = ns;
  __syncthreads();
  for (int off = 128; off; off >>= 1) {
    if (t < off) { red[t] += red[t + off]; redi[t] += redi[t + off]; }
    __syncthreads();
  }
  if (t == 0) {
    int n = redi[0];
    out[0] = -red[0] / (float)n;
    out[1 + 2 * n_host] = (float)n;
  }
}

extern "C" void kernel_launch(void* const* d_in, const int* in_sizes, int n_in,
                              void* d_out, int out_size, void* d_ws, size_t ws_size,
                              hipStream_t stream)
{
  const float* aw     = (const float*)d_in[0];
  const float* astr   = (const float*)d_in[1];
  const float* an     = (const float*)d_in[2];
  const float* nbr    = (const float*)d_in[3];
  const int*   labels = (const int*)d_in[4];
  const float* att    = (const float*)d_in[6];
  const float* proj   = (const float*)d_in[7];
  float* out = (float*)d_out;

  int B = in_sizes[4];
  int C = in_sizes[6];
  int K = (B > 0 && C > 0) ? in_sizes[3] / (B * C) : 0;
  if (C != CC || K != KK) return;
  int n_host = (out_size - 2) / 2;
  int nb = (B + 255) / 256;
  if (nb > 256) return;

  char* w = (char*)d_ws;
  size_t o = 0;
  auto alloc = [&](size_t bytes) { size_t r = o; o += (bytes + 255) & ~(size_t)255; return r; };
  size_t o_wap  = alloc((size_t)B * CC * 4);
  size_t o_q    = alloc((size_t)B * CC * 4);
  size_t o_beta = alloc((size_t)B * 4);
  size_t o_tgt  = alloc((size_t)B * 4);
  size_t o_f0   = alloc((size_t)B * 4);
  size_t o_f1   = alloc((size_t)B * 4);
  size_t o_bc   = alloc((size_t)nb * 4);
  size_t o_lp   = alloc((size_t)nb * 4);
  size_t zstart = o;                       // zeroed-by-memset: h1, h2, cnt, scal
  size_t o_h1   = alloc(65536 * 4);
  size_t o_h2   = alloc(65536 * 4);
  size_t o_cnt  = alloc(64);
  size_t o_scal = alloc(64);
  size_t ztotal = o - zstart;
  if (o > ws_size) return;

  float* wap   = (float*)(w + o_wap);
  float* qbuf  = (float*)(w + o_q);
  float* beta  = (float*)(w + o_beta);
  int*   tgt   = (int*)(w + o_tgt);
  int*   f0    = (int*)(w + o_f0);
  int*   f1    = (int*)(w + o_f1);
  int*   bcnt  = (int*)(w + o_bc);
  float* lossp = (float*)(w + o_lp);
  int*   h1    = (int*)(w + o_h1);
  int*   h2    = (int*)(w + o_h2);
  int*   cnts  = (int*)(w + o_cnt);
  int*   scal  = (int*)(w + o_scal);
  float* taup  = (float*)(scal + 8);

  hipMemsetAsync(w + zstart, 0, ztotal, stream);

  int nbA = (B + 63) / 64;                 // 64 rows/block, 8 waves slice neighbors
  kA      <<<nbA, 512, 0, stream>>>(aw, an, nbr, att, proj, wap, beta, f0, h1, B);
  k3b_sel <<<1, 1024, 0, stream>>>(h1, scal);
  k3c_hist2<<<nb, 256, 0, stream>>>(beta, f0, scal, h2, B);
  k3d_tau <<<1, 1024, 0, stream>>>(h2, scal, taup);
  k4_q    <<<nb, 256, 0, stream>>>(wap, beta, f0, taup, qbuf, tgt, f1,
                                   cnts, bcnt, B);
  k6_out  <<<nb, 256, 0, stream>>>(f1, tgt, labels, bcnt, astr, qbuf, cnts,
                                   out, lossp, n_host, nb, B);
  k7_fin  <<<1, 256, 0, stream>>>(lossp, nb, bcnt, out, n_host);
}

// Round 19
// 125.158 us; speedup vs baseline: 1.1267x; 1.1267x over previous
//
#include <hip/hip_runtime.h>
#include <math.h>

#define CC 10   // classes
#define KK 50   // neighbors

// ---- kA: 64-row tile staged to LDS via pure-copy float4 stream -------------
// 512 threads: stage 8000 contiguous float4 (zero over-fetch, copy-bench
// pattern, ~16 independent loads/lane in flight), one barrier, then 8
// threads/row (same wave) consume neighbor slices from LDS and merge via
// shfl_xor(1,2,4). Epilogue on j==0 lanes. No global-load fragmentation.
__global__ __launch_bounds__(512)
void kA(const float* __restrict__ aw, const float* __restrict__ an,
        const float* __restrict__ nbr, const float* __restrict__ att,
        const float* __restrict__ proj,
        float* __restrict__ wap, float* __restrict__ beta,
        int* __restrict__ flag0, int* __restrict__ hist, int B)
{
  extern __shared__ float tile[];           // 64 rows x 500 floats = 128000 B

  int tid = threadIdx.x;
  int r0  = blockIdx.x * 64;
  int nrow = B - r0; if (nrow > 64) nrow = 64;

  // ---- stage: contiguous float4 copy (fully coalesced, deep MLP) ----------
  {
    const float4* src = reinterpret_cast<const float4*>(nbr + (size_t)r0 * (KK * CC));
    float4* dst = reinterpret_cast<float4*>(tile);
    int nf4 = nrow * 125;                   // 500 floats/row = 125 f4
    for (int f = tid; f < nf4; f += 512) dst[f] = src[f];
  }
  __syncthreads();

  // ---- compute: 8 threads per row (j = slice), same-wave merge -------------
  int j = tid & 7;
  int r = tid >> 3;                         // 0..63
  int row = r0 + r;
  bool valid = (row < B);
  int lrow = valid ? row : 0;

  // uniform coef: coef[c] = att[c] * proj[c][c]^2
  float coef[CC];
#pragma unroll
  for (int c = 0; c < CC; ++c) { float d = proj[c * CC + c]; coef[c] = att[c] * d * d; }

  const float2* anp = reinterpret_cast<const float2*>(an + (size_t)lrow * CC);
  float av[CC];
#pragma unroll
  for (int c2 = 0; c2 < CC / 2; ++c2) { float2 t = anp[c2]; av[2*c2] = t.x; av[2*c2+1] = t.y; }
  float ci[CC];
#pragma unroll
  for (int c = 0; c < CC; ++c) ci[c] = coef[c] * av[c];

  float den = 0.f;
  float qh[CC];
#pragma unroll
  for (int c = 0; c < CC; ++c) qh[c] = 0.f;

  // slice: starts {0,7,14,20,26,32,38,44}, counts {7,7,6,6,6,6,6,6}
  int ks = (j < 2) ? j * 7 : 14 + (j - 2) * 6;
  int kc = (j < 2) ? 7 : 6;
  const float2* seg = reinterpret_cast<const float2*>(&tile[r * 500 + ks * CC]);

#pragma unroll
  for (int t = 0; t < 7; ++t) {
    if (t >= kc) break;
    float nb[CC];
#pragma unroll
    for (int c2 = 0; c2 < CC / 2; ++c2) {
      float2 v = seg[t * (CC / 2) + c2];
      nb[2*c2] = v.x; nb[2*c2+1] = v.y;
    }
    float s = 0.f;
#pragma unroll
    for (int c = 0; c < CC; ++c) s = fmaf(ci[c], nb[c], s);
    s = (s > 0.f) ? s : 0.01f * s;          // leaky_relu (inputs O(1), exp-safe)
    float en[CC]; float sn = 0.f;
#pragma unroll
    for (int c = 0; c < CC; ++c) { en[c] = __expf(nb[c]); sn += en[c]; }
    float e = __expf(s);
    den += e;
    float esc = e * __builtin_amdgcn_rcpf(sn);
#pragma unroll
    for (int c = 0; c < CC; ++c) qh[c] = fmaf(esc, en[c], qh[c]);
  }

  // merge the 8 per-slice partials (lanes 8r..8r+7 of the same wave)
#pragma unroll
  for (int off = 1; off <= 4; off <<= 1) {
    den += __shfl_xor(den, off);
#pragma unroll
    for (int c = 0; c < CC; ++c) qh[c] += __shfl_xor(qh[c], off);
  }

  if (j != 0 || !valid) return;
  float invd = __builtin_amdgcn_rcpf(den);

  // beta = || softmax(an row) - qh/den ||^2
  float ap[CC]; float s2 = 0.f;
#pragma unroll
  for (int c = 0; c < CC; ++c) { ap[c] = __expf(av[c]); s2 += ap[c]; }
  float inv2 = __builtin_amdgcn_rcpf(s2);
  float dd = 0.f;
#pragma unroll
  for (int c = 0; c < CC; ++c) { float d1 = ap[c] * inv2 - qh[c] * invd; dd = fmaf(d1, d1, dd); }
  beta[row] = dd;

  // wap = softmax(aw row); flag0; hist
  const float2* awp = reinterpret_cast<const float2*>(aw + (size_t)row * CC);
  float wv[CC];
#pragma unroll
  for (int c2 = 0; c2 < CC / 2; ++c2) { float2 t = awp[c2]; wv[2*c2] = t.x; wv[2*c2+1] = t.y; }
  float ew[CC]; float sw = 0.f, mxw = 0.f;
#pragma unroll
  for (int c = 0; c < CC; ++c) { ew[c] = __expf(wv[c]); sw += ew[c]; mxw = fmaxf(mxw, ew[c]); }
  float rsw = __builtin_amdgcn_rcpf(sw);
  float2* wq = reinterpret_cast<float2*>(wap + (size_t)row * CC);
#pragma unroll
  for (int c2 = 0; c2 < CC / 2; ++c2) {
    float2 t; t.x = ew[2*c2] * rsw; t.y = ew[2*c2+1] * rsw; wq[c2] = t;
  }
  int f = (mxw * rsw > 0.15f) ? 1 : 0;
  flag0[row] = f;
  if (f) atomicAdd(&hist[__float_as_uint(dd) >> 16], 1);  // beta>=0: order-preserving
}

// ---------------- K3: exact radix select of k-th smallest beta --------------
// scal: [2]=sel_hi [3]=k2 [4]=k ; (float at [8]) = tau
__global__ __launch_bounds__(1024)
void k3b_sel(const int* __restrict__ hist, int* __restrict__ scal)
{
  __shared__ int tmp[1024];
  int t = threadIdx.x;
  int base = t * 64;
  const int4* h4 = reinterpret_cast<const int4*>(hist + base);
  int sum = 0;
#pragma unroll
  for (int jj = 0; jj < 16; ++jj) { int4 v = h4[jj]; sum += v.x + v.y + v.z + v.w; }
  tmp[t] = sum;
  __syncthreads();
  for (int off = 1; off < 1024; off <<= 1) {
    int v = (t >= off) ? tmp[t - off] : 0;
    __syncthreads();
    tmp[t] += v;
    __syncthreads();
  }
  int cumb = tmp[t] - sum;
  int b = tmp[1023];                 // total flagged count == b_count
  int k = (int)(0.5 * (double)b);    // int(ETA*b)
  if (k < 1) k = 1;
  if (t == 0) scal[4] = k;
  if (b > 0 && k > cumb && k <= cumb + sum) {
    int c = cumb;
    for (int jj = 0; jj < 64; ++jj) {
      int h = hist[base + jj];
      if (k <= c + h) { scal[2] = base + jj; scal[3] = k - c; break; }
      c += h;
    }
  }
  if (b == 0 && t == 0) { scal[2] = 0; scal[3] = 1; }
}

__global__ __launch_bounds__(256)
void k3c_hist2(const float* __restrict__ beta, const int* __restrict__ flag0,
               const int* __restrict__ scal, int* __restrict__ hist2, int B)
{
  int i = blockIdx.x * 256 + threadIdx.x;
  if (i >= B) return;
  if (flag0[i]) {
    unsigned key = __float_as_uint(beta[i]);
    if ((int)(key >> 16) == scal[2]) atomicAdd(&hist2[key & 0xFFFF], 1);
  }
}

__global__ __launch_bounds__(1024)
void k3d_tau(const int* __restrict__ hist2, int* __restrict__ scal,
             float* __restrict__ tau)
{
  __shared__ int tmp[1024];
  int t = threadIdx.x;
  int base = t * 64;
  const int4* h4 = reinterpret_cast<const int4*>(hist2 + base);
  int sum = 0;
#pragma unroll
  for (int jj = 0; jj < 16; ++jj) { int4 v = h4[jj]; sum += v.x + v.y + v.z + v.w; }
  tmp[t] = sum;
  __syncthreads();
  for (int off = 1; off < 1024; off <<= 1) {
    int v = (t >= off) ? tmp[t - off] : 0;
    __syncthreads();
    tmp[t] += v;
    __syncthreads();
  }
  int cumb = tmp[t] - sum;
  int k2 = scal[3];
  if (k2 > cumb && k2 <= cumb + sum) {
    int c = cumb;
    for (int jj = 0; jj < 64; ++jj) {
      int h = hist2[base + jj];
      if (k2 <= c + h) {
        unsigned key = (((unsigned)scal[2]) << 16) | (unsigned)(base + jj);
        float bk = __uint_as_float(key);
        *tau = bk / expf(-1.0f);
        break;
      }
      c += h;
    }
  }
}

// ---------------- K4: q, target, mask1, per-block counts --------------------
__global__ __launch_bounds__(256)
void k4_q(const float* __restrict__ wap, const float* __restrict__ beta,
          const int* __restrict__ flag0, const float* __restrict__ tau_p,
          float* __restrict__ qbuf, int* __restrict__ target, int* __restrict__ flag1,
          int* __restrict__ counts, int* __restrict__ blockcnt, int B)
{
  __shared__ int lcnt[CC];
  if (threadIdx.x < CC) lcnt[threadIdx.x] = 0;
  __syncthreads();

  int i = blockIdx.x * 256 + threadIdx.x;
  int f = 0;
  if (i < B) {
    float tau = *tau_p;
    float w[CC];
    const float2* p = reinterpret_cast<const float2*>(wap + (size_t)i * CC);
#pragma unroll
    for (int c = 0; c < CC / 2; ++c) { float2 t = p[c]; w[2*c] = t.x; w[2*c+1] = t.y; }
    float alpha = -__logf(beta[i] / tau);
    float q[CC];
    if (alpha > 1.0f) {
      float s = 0.f;
#pragma unroll
      for (int c = 0; c < CC; ++c) { q[c] = __expf(alpha * __logf(w[c])); s += q[c]; }
#pragma unroll
      for (int c = 0; c < CC; ++c) q[c] = q[c] / s;
    } else {
#pragma unroll
      for (int c = 0; c < CC; ++c) q[c] = w[c];
    }
    float mp = q[0]; int tg = 0;
#pragma unroll
    for (int c = 1; c < CC; ++c) if (q[c] > mp) { mp = q[c]; tg = c; }
    f = (flag0[i] && (mp > 0.1f)) ? 1 : 0;
    float2* qo = reinterpret_cast<float2*>(qbuf + (size_t)i * CC);
#pragma unroll
    for (int c = 0; c < CC / 2; ++c) { float2 t; t.x = q[2*c]; t.y = q[2*c+1]; qo[c] = t; }
    target[i] = tg;
    flag1[i] = f;
    if (f) atomicAdd(&lcnt[tg], 1);   // LDS atomic, contained in block
  }
  __shared__ int red[256];
  red[threadIdx.x] = f;
  __syncthreads();
  for (int off = 128; off; off >>= 1) {
    if (threadIdx.x < off) red[threadIdx.x] += red[threadIdx.x + off];
    __syncthreads();
  }
  if (threadIdx.x == 0) blockcnt[blockIdx.x] = red[0];
  if (threadIdx.x < CC) {
    int v = lcnt[threadIdx.x];
    if (v) atomicAdd(&counts[threadIdx.x], v);   // <=10 global atomics per block
  }
}

// ---------------- K6: self-scan block offsets, weights, outputs, loss parts -
__global__ __launch_bounds__(256)
void k6_out(const int* __restrict__ flag1, const int* __restrict__ target,
            const int* __restrict__ labels, const int* __restrict__ blockcnt,
            const float* __restrict__ a_strong, const float* __restrict__ qbuf,
            const int* __restrict__ counts, float* __restrict__ out,
            float* __restrict__ lossp, int n_host, int nb, int B)
{
  __shared__ int tmp[256];
  __shared__ float wavg_s[CC];
  int t = threadIdx.x;

  int bv = (t < nb) ? blockcnt[t] : 0;
  tmp[t] = bv;
  __syncthreads();
  for (int off = 1; off < 256; off <<= 1) {
    int u = (t >= off) ? tmp[t - off] : 0;
    __syncthreads();
    tmp[t] += u;
    __syncthreads();
  }
  int n    = tmp[255];
  int boff = (blockIdx.x > 0) ? tmp[blockIdx.x - 1] : 0;
  if (t == 0) {
    float wt[CC]; float sumw = 0.f;
    for (int c = 0; c < CC; ++c) {
      int cnt = counts[c];
      float w_ = (cnt > 0) ? 1.0f / logf(1.02f + (float)cnt / (float)n) : 1.0f;
      wt[c] = w_; sumw += w_;
    }
    float meanw = sumw / (float)CC;
    for (int c = 0; c < CC; ++c) wavg_s[c] = wt[c] / sumw * meanw;
  }
  __syncthreads();

  int i = blockIdx.x * 256 + t;
  int f = (i < B) ? flag1[i] : 0;
  tmp[t] = f;
  __syncthreads();
  for (int off = 1; off < 256; off <<= 1) {
    int u = (t >= off) ? tmp[t - off] : 0;
    __syncthreads();
    tmp[t] += u;
    __syncthreads();
  }
  int pos = boff + tmp[t] - f;
  float part = 0.f;
  if (f) {
    out[1 + pos] = (float)target[i];
    out[1 + n_host + pos] = (float)labels[i];
    float x[CC];
    const float2* p = reinterpret_cast<const float2*>(a_strong + (size_t)i * CC);
#pragma unroll
    for (int c = 0; c < CC / 2; ++c) { float2 u2 = p[c]; x[2*c] = u2.x; x[2*c+1] = u2.y; }
    float m = x[0];
#pragma unroll
    for (int c = 1; c < CC; ++c) m = fmaxf(m, x[c]);
    float s = 0.f;
#pragma unroll
    for (int c = 0; c < CC; ++c) s += __expf(x[c] - m);
    float lse = m + __logf(s);
    const float2* qp = reinterpret_cast<const float2*>(qbuf + (size_t)i * CC);
    float q[CC];
#pragma unroll
    for (int c = 0; c < CC / 2; ++c) { float2 u2 = qp[c]; q[2*c] = u2.x; q[2*c+1] = u2.y; }
#pragma unroll
    for (int c = 0; c < CC; ++c) part += wavg_s[c] * q[c] * (x[c] - lse);
  }
  __shared__ float red[256];
  red[t] = part;
  __syncthreads();
  for (int off = 128; off; off >>= 1) {
    if (t < off) red[t] += red[t + off];
    __syncthreads();
  }
  if (t == 0) lossp[blockIdx.x] = red[0];
}

// ---------------- K7: finalize ----------------------------------------------
__global__ __launch_bounds__(256)
void k7_fin(const float* __restrict__ lossp, int nb, const int* __restrict__ blockcnt,
            float* __restrict__ out, int n_host)
{
  __shared__ float red[256];
  __shared__ int   redi[256];
  int t = threadIdx.x;
  float s = 0.f; int ns = 0;
  for (int jj = t; jj < nb; jj += 256) { s += lossp[jj]; ns += blockcnt[jj]; }
  red[t] = s; redi[t] = ns;
  __syncthreads();
  for (int off = 128; off; off >>= 1) {
    if (t < off) { red[t] += red[t + off]; redi[t] += redi[t + off]; }
    __syncthreads();
  }
  if (t == 0) {
    int n = redi[0];
    out[0] = -red[0] / (float)n;
    out[1 + 2 * n_host] = (float)n;
  }
}

extern "C" void kernel_launch(void* const* d_in, const int* in_sizes, int n_in,
                              void* d_out, int out_size, void* d_ws, size_t ws_size,
                              hipStream_t stream)
{
  const float* aw     = (const float*)d_in[0];
  const float* astr   = (const float*)d_in[1];
  const float* an     = (const float*)d_in[2];
  const float* nbr    = (const float*)d_in[3];
  const int*   labels = (const int*)d_in[4];
  const float* att    = (const float*)d_in[6];
  const float* proj   = (const float*)d_in[7];
  float* out = (float*)d_out;

  int B = in_sizes[4];
  int C = in_sizes[6];
  int K = (B > 0 && C > 0) ? in_sizes[3] / (B * C) : 0;
  if (C != CC || K != KK) return;
  int n_host = (out_size - 2) / 2;
  int nb = (B + 255) / 256;
  if (nb > 256) return;

  char* w = (char*)d_ws;
  size_t o = 0;
  auto alloc = [&](size_t bytes) { size_t r = o; o += (bytes + 255) & ~(size_t)255; return r; };
  size_t o_wap  = alloc((size_t)B * CC * 4);
  size_t o_q    = alloc((size_t)B * CC * 4);
  size_t o_beta = alloc((size_t)B * 4);
  size_t o_tgt  = alloc((size_t)B * 4);
  size_t o_f0   = alloc((size_t)B * 4);
  size_t o_f1   = alloc((size_t)B * 4);
  size_t o_bc   = alloc((size_t)nb * 4);
  size_t o_lp   = alloc((size_t)nb * 4);
  size_t zstart = o;                       // zeroed-by-memset: h1, h2, cnt, scal
  size_t o_h1   = alloc(65536 * 4);
  size_t o_h2   = alloc(65536 * 4);
  size_t o_cnt  = alloc(64);
  size_t o_scal = alloc(64);
  size_t ztotal = o - zstart;
  if (o > ws_size) return;

  float* wap   = (float*)(w + o_wap);
  float* qbuf  = (float*)(w + o_q);
  float* beta  = (float*)(w + o_beta);
  int*   tgt   = (int*)(w + o_tgt);
  int*   f0    = (int*)(w + o_f0);
  int*   f1    = (int*)(w + o_f1);
  int*   bcnt  = (int*)(w + o_bc);
  float* lossp = (float*)(w + o_lp);
  int*   h1    = (int*)(w + o_h1);
  int*   h2    = (int*)(w + o_h2);
  int*   cnts  = (int*)(w + o_cnt);
  int*   scal  = (int*)(w + o_scal);
  float* taup  = (float*)(scal + 8);

  hipMemsetAsync(w + zstart, 0, ztotal, stream);

  int nbA = (B + 63) / 64;                 // 64 rows/block, 512 threads, 128KB LDS
  kA      <<<nbA, 512, 64 * 500 * 4, stream>>>(aw, an, nbr, att, proj, wap, beta, f0, h1, B);
  k3b_sel <<<1, 1024, 0, stream>>>(h1, scal);
  k3c_hist2<<<nb, 256, 0, stream>>>(beta, f0, scal, h2, B);
  k3d_tau <<<1, 1024, 0, stream>>>(h2, scal, taup);
  k4_q    <<<nb, 256, 0, stream>>>(wap, beta, f0, taup, qbuf, tgt, f1,
                                   cnts, bcnt, B);
  k6_out  <<<nb, 256, 0, stream>>>(f1, tgt, labels, bcnt, astr, qbuf, cnts,
                                   out, lossp, n_host, nb, B);
  k7_fin  <<<1, 256, 0, stream>>>(lossp, nb, bcnt, out, n_host);
}

// Round 20
// 119.983 us; speedup vs baseline: 1.1753x; 1.0431x over previous
//
#include <hip/hip_runtime.h>
#include <math.h>

#define CC 10   // classes
#define KK 50   // neighbors

// ---- kA: wave-private 8-row LDS subtile, reg-staged (deep MLP), no barriers -
// Block = 256 thr = 4 waves; wave owns rows [32b+8w, +8). Stage: 16 unrolled
// float4 loads/lane into registers (all in flight at once), then 16 unrolled
// ds_write_b128 (contiguous, optimally packed). 64KB LDS/block -> 2 blocks/CU
// so next block's stage overlaps this block's compute. Compute: 8 lanes/row
// consume LDS neighbor slices; shfl_xor{1,2,4} merge; epilogue on j==0.
__global__ __launch_bounds__(256)
void kA(const float* __restrict__ aw, const float* __restrict__ an,
        const float* __restrict__ nbr, const float* __restrict__ att,
        const float* __restrict__ proj,
        float* __restrict__ wap, float* __restrict__ beta,
        int* __restrict__ flag0, int* __restrict__ hist, int B)
{
  __shared__ float tile[4][4000];           // per-wave 8 rows x 500 floats (64KB)

  int tid  = threadIdx.x;
  int wave = tid >> 6;
  int lane = tid & 63;
  int rbase = blockIdx.x * 32 + wave * 8;   // this wave's first row
  if (rbase >= B) return;                   // wave-uniform; no barriers in kernel

  int nrow = B - rbase; if (nrow > 8) nrow = 8;
  int nf4  = nrow * 125;                    // float4s to stage

  // ---- stage: 16 independent float4 loads -> regs, then 16 ds_writes -------
  const float4* src = reinterpret_cast<const float4*>(nbr + (size_t)rbase * (KK * CC));
  float4 v0,v1,v2,v3,v4,v5,v6,v7,v8,v9,v10,v11,v12,v13,v14,v15;
  {
    int l = lane;
    v0  = src[l];        v1  = src[l + 64];  v2  = src[l + 128]; v3  = src[l + 192];
    v4  = src[l + 256];  v5  = src[l + 320]; v6  = src[l + 384]; v7  = src[l + 448];
    v8  = src[l + 512];  v9  = src[l + 576]; v10 = src[l + 640]; v11 = src[l + 704];
    v12 = src[l + 768];  v13 = src[l + 832]; v14 = src[l + 896];
    v15 = (l + 960 < nf4) ? src[l + 960] : make_float4(0.f, 0.f, 0.f, 0.f);
    // note: indices < 960 are only valid when nf4 == 1000 (full 8 rows);
    // partial tail blocks (B%8 != 0) cannot occur for B multiple of 8, but
    // guard anyway by clamping rbase so reads stay within nbr:
  }
  float4* dst = reinterpret_cast<float4*>(&tile[wave][0]);
  dst[lane]       = v0;  dst[lane + 64]  = v1;  dst[lane + 128] = v2;  dst[lane + 192] = v3;
  dst[lane + 256] = v4;  dst[lane + 320] = v5;  dst[lane + 384] = v6;  dst[lane + 448] = v7;
  dst[lane + 512] = v8;  dst[lane + 576] = v9;  dst[lane + 640] = v10; dst[lane + 704] = v11;
  dst[lane + 768] = v12; dst[lane + 832] = v13; dst[lane + 896] = v14;
  if (lane + 960 < 1000) dst[lane + 960] = v15;
  asm volatile("s_waitcnt lgkmcnt(0)" ::: "memory");
  __builtin_amdgcn_sched_barrier(0);

  // ---- compute: 8 lanes per row (r = lane>>3, slice j = lane&7) ------------
  int r = lane >> 3;
  int j = lane & 7;
  int row = rbase + r;
  bool valid = (row < B);
  int lrow = valid ? row : rbase;

  float coef[CC];
#pragma unroll
  for (int c = 0; c < CC; ++c) { float d = proj[c * CC + c]; coef[c] = att[c] * d * d; }

  const float2* anp = reinterpret_cast<const float2*>(an + (size_t)lrow * CC);
  float av[CC];
#pragma unroll
  for (int c2 = 0; c2 < CC / 2; ++c2) { float2 t = anp[c2]; av[2*c2] = t.x; av[2*c2+1] = t.y; }
  float ci[CC];
#pragma unroll
  for (int c = 0; c < CC; ++c) ci[c] = coef[c] * av[c];

  float den = 0.f;
  float qh[CC];
#pragma unroll
  for (int c = 0; c < CC; ++c) qh[c] = 0.f;

  // slice: starts {0,7,14,20,26,32,38,44}, counts {7,7,6,6,6,6,6,6}
  int ks = (j < 2) ? j * 7 : 14 + (j - 2) * 6;
  int kc = (j < 2) ? 7 : 6;
  const float2* seg = reinterpret_cast<const float2*>(&tile[wave][r * 500 + ks * CC]);

#pragma unroll
  for (int t = 0; t < 7; ++t) {
    if (t >= kc) break;
    float nb[CC];
#pragma unroll
    for (int c2 = 0; c2 < CC / 2; ++c2) {
      float2 v = seg[t * (CC / 2) + c2];
      nb[2*c2] = v.x; nb[2*c2+1] = v.y;
    }
    float s = 0.f;
#pragma unroll
    for (int c = 0; c < CC; ++c) s = fmaf(ci[c], nb[c], s);
    s = (s > 0.f) ? s : 0.01f * s;          // leaky_relu (inputs O(1), exp-safe)
    float en[CC]; float sn = 0.f;
#pragma unroll
    for (int c = 0; c < CC; ++c) { en[c] = __expf(nb[c]); sn += en[c]; }
    float e = __expf(s);
    den += e;
    float esc = e * __builtin_amdgcn_rcpf(sn);
#pragma unroll
    for (int c = 0; c < CC; ++c) qh[c] = fmaf(esc, en[c], qh[c]);
  }

  // merge 8 per-slice partials (lanes of the same 8-lane row group)
#pragma unroll
  for (int off = 1; off <= 4; off <<= 1) {
    den += __shfl_xor(den, off);
#pragma unroll
    for (int c = 0; c < CC; ++c) qh[c] += __shfl_xor(qh[c], off);
  }
  float invd = __builtin_amdgcn_rcpf(den);

  // epilogue (all lanes compute; j==0 stores)
  float ap[CC]; float s2 = 0.f;
#pragma unroll
  for (int c = 0; c < CC; ++c) { ap[c] = __expf(av[c]); s2 += ap[c]; }
  float inv2 = __builtin_amdgcn_rcpf(s2);
  float dd = 0.f;
#pragma unroll
  for (int c = 0; c < CC; ++c) { float d1 = ap[c] * inv2 - qh[c] * invd; dd = fmaf(d1, d1, dd); }

  const float2* awp = reinterpret_cast<const float2*>(aw + (size_t)lrow * CC);
  float wv[CC];
#pragma unroll
  for (int c2 = 0; c2 < CC / 2; ++c2) { float2 t = awp[c2]; wv[2*c2] = t.x; wv[2*c2+1] = t.y; }
  float ew[CC]; float sw = 0.f, mxw = 0.f;
#pragma unroll
  for (int c = 0; c < CC; ++c) { ew[c] = __expf(wv[c]); sw += ew[c]; mxw = fmaxf(mxw, ew[c]); }
  float rsw = __builtin_amdgcn_rcpf(sw);

  if (j == 0 && valid) {
    beta[row] = dd;
    float2* wq = reinterpret_cast<float2*>(wap + (size_t)row * CC);
#pragma unroll
    for (int c2 = 0; c2 < CC / 2; ++c2) {
      float2 t; t.x = ew[2*c2] * rsw; t.y = ew[2*c2+1] * rsw; wq[c2] = t;
    }
    int f = (mxw * rsw > 0.15f) ? 1 : 0;
    flag0[row] = f;
    if (f) atomicAdd(&hist[__float_as_uint(dd) >> 16], 1);  // beta>=0: order-preserving
  }
}

// ---------------- K3: exact radix select of k-th smallest beta --------------
// scal: [2]=sel_hi [3]=k2 [4]=k ; (float at [8]) = tau
__global__ __launch_bounds__(1024)
void k3b_sel(const int* __restrict__ hist, int* __restrict__ scal)
{
  __shared__ int tmp[1024];
  int t = threadIdx.x;
  int base = t * 64;
  const int4* h4 = reinterpret_cast<const int4*>(hist + base);
  int sum = 0;
#pragma unroll
  for (int jj = 0; jj < 16; ++jj) { int4 v = h4[jj]; sum += v.x + v.y + v.z + v.w; }
  tmp[t] = sum;
  __syncthreads();
  for (int off = 1; off < 1024; off <<= 1) {
    int v = (t >= off) ? tmp[t - off] : 0;
    __syncthreads();
    tmp[t] += v;
    __syncthreads();
  }
  int cumb = tmp[t] - sum;
  int b = tmp[1023];                 // total flagged count == b_count
  int k = (int)(0.5 * (double)b);    // int(ETA*b)
  if (k < 1) k = 1;
  if (t == 0) scal[4] = k;
  if (b > 0 && k > cumb && k <= cumb + sum) {
    int c = cumb;
    for (int jj = 0; jj < 64; ++jj) {
      int h = hist[base + jj];
      if (k <= c + h) { scal[2] = base + jj; scal[3] = k - c; break; }
      c += h;
    }
  }
  if (b == 0 && t == 0) { scal[2] = 0; scal[3] = 1; }
}

__global__ __launch_bounds__(256)
void k3c_hist2(const float* __restrict__ beta, const int* __restrict__ flag0,
               const int* __restrict__ scal, int* __restrict__ hist2, int B)
{
  int i = blockIdx.x * 256 + threadIdx.x;
  if (i >= B) return;
  if (flag0[i]) {
    unsigned key = __float_as_uint(beta[i]);
    if ((int)(key >> 16) == scal[2]) atomicAdd(&hist2[key & 0xFFFF], 1);
  }
}

__global__ __launch_bounds__(1024)
void k3d_tau(const int* __restrict__ hist2, int* __restrict__ scal,
             float* __restrict__ tau)
{
  __shared__ int tmp[1024];
  int t = threadIdx.x;
  int base = t * 64;
  const int4* h4 = reinterpret_cast<const int4*>(hist2 + base);
  int sum = 0;
#pragma unroll
  for (int jj = 0; jj < 16; ++jj) { int4 v = h4[jj]; sum += v.x + v.y + v.z + v.w; }
  tmp[t] = sum;
  __syncthreads();
  for (int off = 1; off < 1024; off <<= 1) {
    int v = (t >= off) ? tmp[t - off] : 0;
    __syncthreads();
    tmp[t] += v;
    __syncthreads();
  }
  int cumb = tmp[t] - sum;
  int k2 = scal[3];
  if (k2 > cumb && k2 <= cumb + sum) {
    int c = cumb;
    for (int jj = 0; jj < 64; ++jj) {
      int h = hist2[base + jj];
      if (k2 <= c + h) {
        unsigned key = (((unsigned)scal[2]) << 16) | (unsigned)(base + jj);
        float bk = __uint_as_float(key);
        *tau = bk / expf(-1.0f);
        break;
      }
      c += h;
    }
  }
}

// ---------------- K4: q, target, mask1, per-block counts --------------------
__global__ __launch_bounds__(256)
void k4_q(const float* __restrict__ wap, const float* __restrict__ beta,
          const int* __restrict__ flag0, const float* __restrict__ tau_p,
          float* __restrict__ qbuf, int* __restrict__ target, int* __restrict__ flag1,
          int* __restrict__ counts, int* __restrict__ blockcnt, int B)
{
  __shared__ int lcnt[CC];
  if (threadIdx.x < CC) lcnt[threadIdx.x] = 0;
  __syncthreads();

  int i = blockIdx.x * 256 + threadIdx.x;
  int f = 0;
  if (i < B) {
    float tau = *tau_p;
    float w[CC];
    const float2* p = reinterpret_cast<const float2*>(wap + (size_t)i * CC);
#pragma unroll
    for (int c = 0; c < CC / 2; ++c) { float2 t = p[c]; w[2*c] = t.x; w[2*c+1] = t.y; }
    float alpha = -__logf(beta[i] / tau);
    float q[CC];
    if (alpha > 1.0f) {
      float s = 0.f;
#pragma unroll
      for (int c = 0; c < CC; ++c) { q[c] = __expf(alpha * __logf(w[c])); s += q[c]; }
#pragma unroll
      for (int c = 0; c < CC; ++c) q[c] = q[c] / s;
    } else {
#pragma unroll
      for (int c = 0; c < CC; ++c) q[c] = w[c];
    }
    float mp = q[0]; int tg = 0;
#pragma unroll
    for (int c = 1; c < CC; ++c) if (q[c] > mp) { mp = q[c]; tg = c; }
    f = (flag0[i] && (mp > 0.1f)) ? 1 : 0;
    float2* qo = reinterpret_cast<float2*>(qbuf + (size_t)i * CC);
#pragma unroll
    for (int c = 0; c < CC / 2; ++c) { float2 t; t.x = q[2*c]; t.y = q[2*c+1]; qo[c] = t; }
    target[i] = tg;
    flag1[i] = f;
    if (f) atomicAdd(&lcnt[tg], 1);   // LDS atomic, contained in block
  }
  __shared__ int red[256];
  red[threadIdx.x] = f;
  __syncthreads();
  for (int off = 128; off; off >>= 1) {
    if (threadIdx.x < off) red[threadIdx.x] += red[threadIdx.x + off];
    __syncthreads();
  }
  if (threadIdx.x == 0) blockcnt[blockIdx.x] = red[0];
  if (threadIdx.x < CC) {
    int v = lcnt[threadIdx.x];
    if (v) atomicAdd(&counts[threadIdx.x], v);   // <=10 global atomics per block
  }
}

// ---------------- K6: self-scan block offsets, weights, outputs, loss parts -
__global__ __launch_bounds__(256)
void k6_out(const int* __restrict__ flag1, const int* __restrict__ target,
            const int* __restrict__ labels, const int* __restrict__ blockcnt,
            const float* __restrict__ a_strong, const float* __restrict__ qbuf,
            const int* __restrict__ counts, float* __restrict__ out,
            float* __restrict__ lossp, int n_host, int nb, int B)
{
  __shared__ int tmp[256];
  __shared__ float wavg_s[CC];
  int t = threadIdx.x;

  int bv = (t < nb) ? blockcnt[t] : 0;
  tmp[t] = bv;
  __syncthreads();
  for (int off = 1; off < 256; off <<= 1) {
    int u = (t >= off) ? tmp[t - off] : 0;
    __syncthreads();
    tmp[t] += u;
    __syncthreads();
  }
  int n    = tmp[255];
  int boff = (blockIdx.x > 0) ? tmp[blockIdx.x - 1] : 0;
  if (t == 0) {
    float wt[CC]; float sumw = 0.f;
    for (int c = 0; c < CC; ++c) {
      int cnt = counts[c];
      float w_ = (cnt > 0) ? 1.0f / logf(1.02f + (float)cnt / (float)n) : 1.0f;
      wt[c] = w_; sumw += w_;
    }
    float meanw = sumw / (float)CC;
    for (int c = 0; c < CC; ++c) wavg_s[c] = wt[c] / sumw * meanw;
  }
  __syncthreads();

  int i = blockIdx.x * 256 + t;
  int f = (i < B) ? flag1[i] : 0;
  tmp[t] = f;
  __syncthreads();
  for (int off = 1; off < 256; off <<= 1) {
    int u = (t >= off) ? tmp[t - off] : 0;
    __syncthreads();
    tmp[t] += u;
    __syncthreads();
  }
  int pos = boff + tmp[t] - f;
  float part = 0.f;
  if (f) {
    out[1 + pos] = (float)target[i];
    out[1 + n_host + pos] = (float)labels[i];
    float x[CC];
    const float2* p = reinterpret_cast<const float2*>(a_strong + (size_t)i * CC);
#pragma unroll
    for (int c = 0; c < CC / 2; ++c) { float2 u2 = p[c]; x[2*c] = u2.x; x[2*c+1] = u2.y; }
    float m = x[0];
#pragma unroll
    for (int c = 1; c < CC; ++c) m = fmaxf(m, x[c]);
    float s = 0.f;
#pragma unroll
    for (int c = 0; c < CC; ++c) s += __expf(x[c] - m);
    float lse = m + __logf(s);
    const float2* qp = reinterpret_cast<const float2*>(qbuf + (size_t)i * CC);
    float q[CC];
#pragma unroll
    for (int c = 0; c < CC / 2; ++c) { float2 u2 = qp[c]; q[2*c] = u2.x; q[2*c+1] = u2.y; }
#pragma unroll
    for (int c = 0; c < CC; ++c) part += wavg_s[c] * q[c] * (x[c] - lse);
  }
  __shared__ float red[256];
  red[t] = part;
  __syncthreads();
  for (int off = 128; off; off >>= 1) {
    if (t < off) red[t] += red[t + off];
    __syncthreads();
  }
  if (t == 0) lossp[blockIdx.x] = red[0];
}

// ---------------- K7: finalize ----------------------------------------------
__global__ __launch_bounds__(256)
void k7_fin(const float* __restrict__ lossp, int nb, const int* __restrict__ blockcnt,
            float* __restrict__ out, int n_host)
{
  __shared__ float red[256];
  __shared__ int   redi[256];
  int t = threadIdx.x;
  float s = 0.f; int ns = 0;
  for (int jj = t; jj < nb; jj += 256) { s += lossp[jj]; ns += blockcnt[jj]; }
  red[t] = s; redi[t] = ns;
  __syncthreads();
  for (int off = 128; off; off >>= 1) {
    if (t < off) { red[t] += red[t + off]; redi[t] += redi[t + off]; }
    __syncthreads();
  }
  if (t == 0) {
    int n = redi[0];
    out[0] = -red[0] / (float)n;
    out[1 + 2 * n_host] = (float)n;
  }
}

extern "C" void kernel_launch(void* const* d_in, const int* in_sizes, int n_in,
                              void* d_out, int out_size, void* d_ws, size_t ws_size,
                              hipStream_t stream)
{
  const float* aw     = (const float*)d_in[0];
  const float* astr   = (const float*)d_in[1];
  const float* an     = (const float*)d_in[2];
  const float* nbr    = (const float*)d_in[3];
  const int*   labels = (const int*)d_in[4];
  const float* att    = (const float*)d_in[6];
  const float* proj   = (const float*)d_in[7];
  float* out = (float*)d_out;

  int B = in_sizes[4];
  int C = in_sizes[6];
  int K = (B > 0 && C > 0) ? in_sizes[3] / (B * C) : 0;
  if (C != CC || K != KK) return;
  if (B % 8 != 0) return;                  // stage assumes whole 8-row waves
  int n_host = (out_size - 2) / 2;
  int nb = (B + 255) / 256;
  if (nb > 256) return;

  char* w = (char*)d_ws;
  size_t o = 0;
  auto alloc = [&](size_t bytes) { size_t r = o; o += (bytes + 255) & ~(size_t)255; return r; };
  size_t o_wap  = alloc((size_t)B * CC * 4);
  size_t o_q    = alloc((size_t)B * CC * 4);
  size_t o_beta = alloc((size_t)B * 4);
  size_t o_tgt  = alloc((size_t)B * 4);
  size_t o_f0   = alloc((size_t)B * 4);
  size_t o_f1   = alloc((size_t)B * 4);
  size_t o_bc   = alloc((size_t)nb * 4);
  size_t o_lp   = alloc((size_t)nb * 4);
  size_t zstart = o;                       // zeroed-by-memset: h1, h2, cnt, scal
  size_t o_h1   = alloc(65536 * 4);
  size_t o_h2   = alloc(65536 * 4);
  size_t o_cnt  = alloc(64);
  size_t o_scal = alloc(64);
  size_t ztotal = o - zstart;
  if (o > ws_size) return;

  float* wap   = (float*)(w + o_wap);
  float* qbuf  = (float*)(w + o_q);
  float* beta  = (float*)(w + o_beta);
  int*   tgt   = (int*)(w + o_tgt);
  int*   f0    = (int*)(w + o_f0);
  int*   f1    = (int*)(w + o_f1);
  int*   bcnt  = (int*)(w + o_bc);
  float* lossp = (float*)(w + o_lp);
  int*   h1    = (int*)(w + o_h1);
  int*   h2    = (int*)(w + o_h2);
  int*   cnts  = (int*)(w + o_cnt);
  int*   scal  = (int*)(w + o_scal);
  float* taup  = (float*)(scal + 8);

  hipMemsetAsync(w + zstart, 0, ztotal, stream);

  int nbA = (B + 31) / 32;                 // 32 rows/block, 4 waves x 8 rows, 64KB LDS
  kA      <<<nbA, 256, 0, stream>>>(aw, an, nbr, att, proj, wap, beta, f0, h1, B);
  k3b_sel <<<1, 1024, 0, stream>>>(h1, scal);
  k3c_hist2<<<nb, 256, 0, stream>>>(beta, f0, scal, h2, B);
  k3d_tau <<<1, 1024, 0, stream>>>(h2, scal, taup);
  k4_q    <<<nb, 256, 0, stream>>>(wap, beta, f0, taup, qbuf, tgt, f1,
                                   cnts, bcnt, B);
  k6_out  <<<nb, 256, 0, stream>>>(f1, tgt, labels, bcnt, astr, qbuf, cnts,
                                   out, lossp, n_host, nb, B);
  k7_fin  <<<1, 256, 0, stream>>>(lossp, nb, bcnt, out, n_host);
}

// Round 21
// 109.856 us; speedup vs baseline: 1.2836x; 1.0922x over previous
//
#include <hip/hip_runtime.h>
#include <math.h>

#define CC 10   // classes
#define KK 50   // neighbors

// ---- kA: R17's wave-slice structure repacked into 256 blocks ---------------
// 1024 thr = 16 waves = 4 row-groups x 4 k-slices (13/13/12/12). Per-wave
// access pattern identical to R17 (lane=row, wave-uniform slice -> 1.6 TB/s
// at 16 waves/CU). Grid = 256 blocks: the proven low-dispatch-overhead regime
// (total-kA = 11-14us at 256 blocks vs 30-42us at >=1024 blocks, R8-R20 law).
__global__ __launch_bounds__(1024)
void kA(const float* __restrict__ aw, const float* __restrict__ an,
        const float* __restrict__ nbr, const float* __restrict__ att,
        const float* __restrict__ proj,
        float* __restrict__ wap, float* __restrict__ beta,
        int* __restrict__ flag0, int* __restrict__ hist, int B)
{
  __shared__ float part[12][64][11];        // slices 1..3 x 4 row-groups (34KB)

  int tid  = threadIdx.x;
  int wave = tid >> 6;                      // 0..15
  int lane = tid & 63;
  int g    = wave >> 2;                     // row-group 0..3
  int sl   = wave & 3;                      // k-slice 0..3
  int row  = blockIdx.x * 256 + g * 64 + lane;
  bool valid = (row < B);
  int lrow = valid ? row : 0;               // clamp for safe loads

  // uniform coef: coef[c] = att[c] * proj[c][c]^2
  float coef[CC];
#pragma unroll
  for (int c = 0; c < CC; ++c) { float d = proj[c * CC + c]; coef[c] = att[c] * d * d; }

  const float2* anp = reinterpret_cast<const float2*>(an + (size_t)lrow * CC);
  float av[CC];
#pragma unroll
  for (int c2 = 0; c2 < CC / 2; ++c2) { float2 t = anp[c2]; av[2*c2] = t.x; av[2*c2+1] = t.y; }
  float ci[CC];
#pragma unroll
  for (int c = 0; c < CC; ++c) ci[c] = coef[c] * av[c];

  float den = 0.f;
  float qh[CC];
#pragma unroll
  for (int c = 0; c < CC; ++c) qh[c] = 0.f;

  // k-slice: starts {0,13,26,38}, counts {13,13,12,12}
  int ks = (sl == 0) ? 0 : (sl == 1) ? 13 : (sl == 2) ? 26 : 38;
  int kc = (sl < 2) ? 13 : 12;
  const float2* rowp = reinterpret_cast<const float2*>(nbr + (size_t)lrow * (KK * CC))
                       + ks * (CC / 2);

#pragma unroll 4
  for (int t = 0; t < 13; ++t) {
    if (t >= kc) break;                     // wave-uniform
    float nb[CC];
#pragma unroll
    for (int c2 = 0; c2 < CC / 2; ++c2) {
      float2 v = rowp[t * (CC / 2) + c2];
      nb[2*c2] = v.x; nb[2*c2+1] = v.y;
    }
    float s = 0.f;
#pragma unroll
    for (int c = 0; c < CC; ++c) s = fmaf(ci[c], nb[c], s);
    s = (s > 0.f) ? s : 0.01f * s;          // leaky_relu (inputs O(1), exp-safe)
    float en[CC]; float sn = 0.f;
#pragma unroll
    for (int c = 0; c < CC; ++c) { en[c] = __expf(nb[c]); sn += en[c]; }
    float e = __expf(s);
    den += e;
    float esc = e * __builtin_amdgcn_rcpf(sn);
#pragma unroll
    for (int c = 0; c < CC; ++c) qh[c] = fmaf(esc, en[c], qh[c]);
  }

  if (sl > 0) {
    float* p = &part[g * 3 + (sl - 1)][lane][0];
    p[0] = den;
#pragma unroll
    for (int c = 0; c < CC; ++c) p[1 + c] = qh[c];
  }
  __syncthreads();
  if (sl != 0) return;

  // slice-0 waves: merge the 3 partials of this row-group (fixed order)
#pragma unroll
  for (int w = 0; w < 3; ++w) {
    const float* p = &part[g * 3 + w][lane][0];
    den += p[0];
#pragma unroll
    for (int c = 0; c < CC; ++c) qh[c] += p[1 + c];
  }
  if (!valid) return;
  float invd = __builtin_amdgcn_rcpf(den);

  // beta = || softmax(an row) - qh/den ||^2
  float ap[CC]; float s2 = 0.f;
#pragma unroll
  for (int c = 0; c < CC; ++c) { ap[c] = __expf(av[c]); s2 += ap[c]; }
  float inv2 = __builtin_amdgcn_rcpf(s2);
  float dd = 0.f;
#pragma unroll
  for (int c = 0; c < CC; ++c) { float d1 = ap[c] * inv2 - qh[c] * invd; dd = fmaf(d1, d1, dd); }
  beta[row] = dd;

  // wap = softmax(aw row); flag0; hist
  const float2* awp = reinterpret_cast<const float2*>(aw + (size_t)row * CC);
  float wv[CC];
#pragma unroll
  for (int c2 = 0; c2 < CC / 2; ++c2) { float2 t = awp[c2]; wv[2*c2] = t.x; wv[2*c2+1] = t.y; }
  float ew[CC]; float sw = 0.f, mxw = 0.f;
#pragma unroll
  for (int c = 0; c < CC; ++c) { ew[c] = __expf(wv[c]); sw += ew[c]; mxw = fmaxf(mxw, ew[c]); }
  float rsw = __builtin_amdgcn_rcpf(sw);
  float2* wq = reinterpret_cast<float2*>(wap + (size_t)row * CC);
#pragma unroll
  for (int c2 = 0; c2 < CC / 2; ++c2) {
    float2 t; t.x = ew[2*c2] * rsw; t.y = ew[2*c2+1] * rsw; wq[c2] = t;
  }
  int f = (mxw * rsw > 0.15f) ? 1 : 0;
  flag0[row] = f;
  if (f) atomicAdd(&hist[__float_as_uint(dd) >> 16], 1);  // beta>=0: order-preserving
}

// ---------------- K3: exact radix select of k-th smallest beta --------------
// scal: [2]=sel_hi [3]=k2 [4]=k ; (float at [8]) = tau
__global__ __launch_bounds__(1024)
void k3b_sel(const int* __restrict__ hist, int* __restrict__ scal)
{
  __shared__ int tmp[1024];
  int t = threadIdx.x;
  int base = t * 64;
  const int4* h4 = reinterpret_cast<const int4*>(hist + base);
  int sum = 0;
#pragma unroll
  for (int jj = 0; jj < 16; ++jj) { int4 v = h4[jj]; sum += v.x + v.y + v.z + v.w; }
  tmp[t] = sum;
  __syncthreads();
  for (int off = 1; off < 1024; off <<= 1) {
    int v = (t >= off) ? tmp[t - off] : 0;
    __syncthreads();
    tmp[t] += v;
    __syncthreads();
  }
  int cumb = tmp[t] - sum;
  int b = tmp[1023];                 // total flagged count == b_count
  int k = (int)(0.5 * (double)b);    // int(ETA*b)
  if (k < 1) k = 1;
  if (t == 0) scal[4] = k;
  if (b > 0 && k > cumb && k <= cumb + sum) {
    int c = cumb;
    for (int jj = 0; jj < 64; ++jj) {
      int h = hist[base + jj];
      if (k <= c + h) { scal[2] = base + jj; scal[3] = k - c; break; }
      c += h;
    }
  }
  if (b == 0 && t == 0) { scal[2] = 0; scal[3] = 1; }
}

__global__ __launch_bounds__(256)
void k3c_hist2(const float* __restrict__ beta, const int* __restrict__ flag0,
               const int* __restrict__ scal, int* __restrict__ hist2, int B)
{
  int i = blockIdx.x * 256 + threadIdx.x;
  if (i >= B) return;
  if (flag0[i]) {
    unsigned key = __float_as_uint(beta[i]);
    if ((int)(key >> 16) == scal[2]) atomicAdd(&hist2[key & 0xFFFF], 1);
  }
}

__global__ __launch_bounds__(1024)
void k3d_tau(const int* __restrict__ hist2, int* __restrict__ scal,
             float* __restrict__ tau)
{
  __shared__ int tmp[1024];
  int t = threadIdx.x;
  int base = t * 64;
  const int4* h4 = reinterpret_cast<const int4*>(hist2 + base);
  int sum = 0;
#pragma unroll
  for (int jj = 0; jj < 16; ++jj) { int4 v = h4[jj]; sum += v.x + v.y + v.z + v.w; }
  tmp[t] = sum;
  __syncthreads();
  for (int off = 1; off < 1024; off <<= 1) {
    int v = (t >= off) ? tmp[t - off] : 0;
    __syncthreads();
    tmp[t] += v;
    __syncthreads();
  }
  int cumb = tmp[t] - sum;
  int k2 = scal[3];
  if (k2 > cumb && k2 <= cumb + sum) {
    int c = cumb;
    for (int jj = 0; jj < 64; ++jj) {
      int h = hist2[base + jj];
      if (k2 <= c + h) {
        unsigned key = (((unsigned)scal[2]) << 16) | (unsigned)(base + jj);
        float bk = __uint_as_float(key);
        *tau = bk / expf(-1.0f);
        break;
      }
      c += h;
    }
  }
}

// ---------------- K4: q, target, mask1, per-block counts --------------------
__global__ __launch_bounds__(256)
void k4_q(const float* __restrict__ wap, const float* __restrict__ beta,
          const int* __restrict__ flag0, const float* __restrict__ tau_p,
          float* __restrict__ qbuf, int* __restrict__ target, int* __restrict__ flag1,
          int* __restrict__ counts, int* __restrict__ blockcnt, int B)
{
  __shared__ int lcnt[CC];
  if (threadIdx.x < CC) lcnt[threadIdx.x] = 0;
  __syncthreads();

  int i = blockIdx.x * 256 + threadIdx.x;
  int f = 0;
  if (i < B) {
    float tau = *tau_p;
    float w[CC];
    const float2* p = reinterpret_cast<const float2*>(wap + (size_t)i * CC);
#pragma unroll
    for (int c = 0; c < CC / 2; ++c) { float2 t = p[c]; w[2*c] = t.x; w[2*c+1] = t.y; }
    float alpha = -__logf(beta[i] / tau);
    float q[CC];
    if (alpha > 1.0f) {
      float s = 0.f;
#pragma unroll
      for (int c = 0; c < CC; ++c) { q[c] = __expf(alpha * __logf(w[c])); s += q[c]; }
#pragma unroll
      for (int c = 0; c < CC; ++c) q[c] = q[c] / s;
    } else {
#pragma unroll
      for (int c = 0; c < CC; ++c) q[c] = w[c];
    }
    float mp = q[0]; int tg = 0;
#pragma unroll
    for (int c = 1; c < CC; ++c) if (q[c] > mp) { mp = q[c]; tg = c; }
    f = (flag0[i] && (mp > 0.1f)) ? 1 : 0;
    float2* qo = reinterpret_cast<float2*>(qbuf + (size_t)i * CC);
#pragma unroll
    for (int c = 0; c < CC / 2; ++c) { float2 t; t.x = q[2*c]; t.y = q[2*c+1]; qo[c] = t; }
    target[i] = tg;
    flag1[i] = f;
    if (f) atomicAdd(&lcnt[tg], 1);   // LDS atomic, contained in block
  }
  __shared__ int red[256];
  red[threadIdx.x] = f;
  __syncthreads();
  for (int off = 128; off; off >>= 1) {
    if (threadIdx.x < off) red[threadIdx.x] += red[threadIdx.x + off];
    __syncthreads();
  }
  if (threadIdx.x == 0) blockcnt[blockIdx.x] = red[0];
  if (threadIdx.x < CC) {
    int v = lcnt[threadIdx.x];
    if (v) atomicAdd(&counts[threadIdx.x], v);   // <=10 global atomics per block
  }
}

// ---------------- K6: self-scan block offsets, weights, outputs, loss parts -
__global__ __launch_bounds__(256)
void k6_out(const int* __restrict__ flag1, const int* __restrict__ target,
            const int* __restrict__ labels, const int* __restrict__ blockcnt,
            const float* __restrict__ a_strong, const float* __restrict__ qbuf,
            const int* __restrict__ counts, float* __restrict__ out,
            float* __restrict__ lossp, int n_host, int nb, int B)
{
  __shared__ int tmp[256];
  __shared__ float wavg_s[CC];
  int t = threadIdx.x;

  int bv = (t < nb) ? blockcnt[t] : 0;
  tmp[t] = bv;
  __syncthreads();
  for (int off = 1; off < 256; off <<= 1) {
    int u = (t >= off) ? tmp[t - off] : 0;
    __syncthreads();
    tmp[t] += u;
    __syncthreads();
  }
  int n    = tmp[255];
  int boff = (blockIdx.x > 0) ? tmp[blockIdx.x - 1] : 0;
  if (t == 0) {
    float wt[CC]; float sumw = 0.f;
    for (int c = 0; c < CC; ++c) {
      int cnt = counts[c];
      float w_ = (cnt > 0) ? 1.0f / logf(1.02f + (float)cnt / (float)n) : 1.0f;
      wt[c] = w_; sumw += w_;
    }
    float meanw = sumw / (float)CC;
    for (int c = 0; c < CC; ++c) wavg_s[c] = wt[c] / sumw * meanw;
  }
  __syncthreads();

  int i = blockIdx.x * 256 + t;
  int f = (i < B) ? flag1[i] : 0;
  tmp[t] = f;
  __syncthreads();
  for (int off = 1; off < 256; off <<= 1) {
    int u = (t >= off) ? tmp[t - off] : 0;
    __syncthreads();
    tmp[t] += u;
    __syncthreads();
  }
  int pos = boff + tmp[t] - f;
  float part = 0.f;
  if (f) {
    out[1 + pos] = (float)target[i];
    out[1 + n_host + pos] = (float)labels[i];
    float x[CC];
    const float2* p = reinterpret_cast<const float2*>(a_strong + (size_t)i * CC);
#pragma unroll
    for (int c = 0; c < CC / 2; ++c) { float2 u2 = p[c]; x[2*c] = u2.x; x[2*c+1] = u2.y; }
    float m = x[0];
#pragma unroll
    for (int c = 1; c < CC; ++c) m = fmaxf(m, x[c]);
    float s = 0.f;
#pragma unroll
    for (int c = 0; c < CC; ++c) s += __expf(x[c] - m);
    float lse = m + __logf(s);
    const float2* qp = reinterpret_cast<const float2*>(qbuf + (size_t)i * CC);
    float q[CC];
#pragma unroll
    for (int c = 0; c < CC / 2; ++c) { float2 u2 = qp[c]; q[2*c] = u2.x; q[2*c+1] = u2.y; }
#pragma unroll
    for (int c = 0; c < CC; ++c) part += wavg_s[c] * q[c] * (x[c] - lse);
  }
  __shared__ float red[256];
  red[t] = part;
  __syncthreads();
  for (int off = 128; off; off >>= 1) {
    if (t < off) red[t] += red[t + off];
    __syncthreads();
  }
  if (t == 0) lossp[blockIdx.x] = red[0];
}

// ---------------- K7: finalize ----------------------------------------------
__global__ __launch_bounds__(256)
void k7_fin(const float* __restrict__ lossp, int nb, const int* __restrict__ blockcnt,
            float* __restrict__ out, int n_host)
{
  __shared__ float red[256];
  __shared__ int   redi[256];
  int t = threadIdx.x;
  float s = 0.f; int ns = 0;
  for (int jj = t; jj < nb; jj += 256) { s += lossp[jj]; ns += blockcnt[jj]; }
  red[t] = s; redi[t] = ns;
  __syncthreads();
  for (int off = 128; off; off >>= 1) {
    if (t < off) { red[t] += red[t + off]; redi[t] += redi[t + off]; }
    __syncthreads();
  }
  if (t == 0) {
    int n = redi[0];
    out[0] = -red[0] / (float)n;
    out[1 + 2 * n_host] = (float)n;
  }
}

extern "C" void kernel_launch(void* const* d_in, const int* in_sizes, int n_in,
                              void* d_out, int out_size, void* d_ws, size_t ws_size,
                              hipStream_t stream)
{
  const float* aw     = (const float*)d_in[0];
  const float* astr   = (const float*)d_in[1];
  const float* an     = (const float*)d_in[2];
  const float* nbr    = (const float*)d_in[3];
  const int*   labels = (const int*)d_in[4];
  const float* att    = (const float*)d_in[6];
  const float* proj   = (const float*)d_in[7];
  float* out = (float*)d_out;

  int B = in_sizes[4];
  int C = in_sizes[6];
  int K = (B > 0 && C > 0) ? in_sizes[3] / (B * C) : 0;
  if (C != CC || K != KK) return;
  int n_host = (out_size - 2) / 2;
  int nb = (B + 255) / 256;
  if (nb > 256) return;

  char* w = (char*)d_ws;
  size_t o = 0;
  auto alloc = [&](size_t bytes) { size_t r = o; o += (bytes + 255) & ~(size_t)255; return r; };
  size_t o_wap  = alloc((size_t)B * CC * 4);
  size_t o_q    = alloc((size_t)B * CC * 4);
  size_t o_beta = alloc((size_t)B * 4);
  size_t o_tgt  = alloc((size_t)B * 4);
  size_t o_f0   = alloc((size_t)B * 4);
  size_t o_f1   = alloc((size_t)B * 4);
  size_t o_bc   = alloc((size_t)nb * 4);
  size_t o_lp   = alloc((size_t)nb * 4);
  size_t zstart = o;                       // zeroed-by-memset: h1, h2, cnt, scal
  size_t o_h1   = alloc(65536 * 4);
  size_t o_h2   = alloc(65536 * 4);
  size_t o_cnt  = alloc(64);
  size_t o_scal = alloc(64);
  size_t ztotal = o - zstart;
  if (o > ws_size) return;

  float* wap   = (float*)(w + o_wap);
  float* qbuf  = (float*)(w + o_q);
  float* beta  = (float*)(w + o_beta);
  int*   tgt   = (int*)(w + o_tgt);
  int*   f0    = (int*)(w + o_f0);
  int*   f1    = (int*)(w + o_f1);
  int*   bcnt  = (int*)(w + o_bc);
  float* lossp = (float*)(w + o_lp);
  int*   h1    = (int*)(w + o_h1);
  int*   h2    = (int*)(w + o_h2);
  int*   cnts  = (int*)(w + o_cnt);
  int*   scal  = (int*)(w + o_scal);
  float* taup  = (float*)(scal + 8);

  hipMemsetAsync(w + zstart, 0, ztotal, stream);

  int nbA = (B + 255) / 256;               // 256 rows/block, 16 waves (4 grp x 4 slice)
  kA      <<<nbA, 1024, 0, stream>>>(aw, an, nbr, att, proj, wap, beta, f0, h1, B);
  k3b_sel <<<1, 1024, 0, stream>>>(h1, scal);
  k3c_hist2<<<nb, 256, 0, stream>>>(beta, f0, scal, h2, B);
  k3d_tau <<<1, 1024, 0, stream>>>(h2, scal, taup);
  k4_q    <<<nb, 256, 0, stream>>>(wap, beta, f0, taup, qbuf, tgt, f1,
                                   cnts, bcnt, B);
  k6_out  <<<nb, 256, 0, stream>>>(f1, tgt, labels, bcnt, astr, qbuf, cnts,
                                   out, lossp, n_host, nb, B);
  k7_fin  <<<1, 256, 0, stream>>>(lossp, nb, bcnt, out, n_host);
}